// Round 6
// baseline (400.848 us; speedup 1.0000x reference)
//
#include <hip/hip_runtime.h>
#include <hip/hip_bf16.h>

// MLP_small_per_feature: per-feature MLP 1 -> 64 -> 64 -> 1, F=256, B=8192.
// v6 = v4 structure + two changes:
//  (1) prep kernel packs w2 -> bf16 in fragment-major order into d_ws; the
//      main kernel's w2 load is 8 fully-coalesced dwordx4 (8 KB/wave, no
//      overfetch). Kills v5's 180 MB FETCH explosion at high wave counts.
//  (2) 256 rows/wave, grid 2048 x 256thr, __launch_bounds__(256,8) ->
//      8 blocks/CU, 32 waves/CU target (v4 was 16 and 60% VALU-idle).
//
// MFMA 16x16x32_bf16 layout (verified rounds 1-5, absmax 0.031):
//   A: row m = lane&15, k = (lane>>4)*8 + i
//   B: col n = lane&15, k = (lane>>4)*8 + i
//   C/D: col n = lane&15, row m = (lane>>4)*4 + r

namespace {

constexpr int kF = 256;
constexpr int kH = 64;
constexpr int kB = 8192;

constexpr int kFPB     = 4;               // features per block (one per wave)
constexpr int kRPB     = 256;             // rows per block
constexpr int kThreads = 256;             // 4 waves
constexpr int kFG      = kF / kFPB;       // 64 feature groups
constexpr int kRG      = kB / kRPB;       // 32 row groups
constexpr int kBlocks  = kFG * kRG;       // 2048 -> 8 blocks/CU
constexpr int kPasses  = kRPB / 16;       // 16

using f32x4  = __attribute__((ext_vector_type(4))) float;
using bf16x4 = __attribute__((ext_vector_type(4))) __bf16;
using bf16x8 = __attribute__((ext_vector_type(8))) __bf16;

// ---- prep: pack w2 (fp32 [F][64][64]) -> bf16 fragment-major ----
// Layout: w2p elem offset ((f*8 + j)*64 + lane)*8, j = t*2+ks. Lane l's
// fragment (t,ks) = w2[f][o=t*16+(l&15)][ks*32+(l>>4)*8 .. +8].
__global__ __launch_bounds__(256)
void pack_w2(const float* __restrict__ w2, __bf16* __restrict__ w2p)
{
  const int wid  = (int)threadIdx.x >> 6;
  const int lane = (int)threadIdx.x & 63;
  const int f    = (int)blockIdx.x * 4 + wid;
  const int l15  = lane & 15;
  const int lg   = lane >> 4;

  const float* w2f = w2 + (size_t)f * (kH * kH);
  #pragma unroll
  for (int t = 0; t < 4; ++t) {
    const int o = t * 16 + l15;
    #pragma unroll
    for (int ks = 0; ks < 2; ++ks) {
      const float* p = w2f + o * kH + ks * 32 + lg * 8;
      const f32x4 lo = *reinterpret_cast<const f32x4*>(p);
      const f32x4 hi = *reinterpret_cast<const f32x4*>(p + 4);
      const bf16x8 v = __builtin_shufflevector(
          __builtin_convertvector(lo, bf16x4),
          __builtin_convertvector(hi, bf16x4), 0, 1, 2, 3, 4, 5, 6, 7);
      *reinterpret_cast<bf16x8*>(
          w2p + (((size_t)f * 8 + t * 2 + ks) * 64 + lane) * 8) = v;
    }
  }
}

__global__ __launch_bounds__(kThreads, 8)
void mlp_pf_v6(const float* __restrict__ x,
               const float* __restrict__ w1,
               const float* __restrict__ b1,
               const __bf16* __restrict__ w2p,
               const float* __restrict__ b2,
               const float* __restrict__ w3,
               const float* __restrict__ b3,
               float* __restrict__ out)
{
  __shared__ float xs[kFPB][kRPB];        // 4 KB
  __shared__ float outb[kRPB][kFPB + 1];  // 5.1 KB (pad: conflict-free)

  const int tid  = (int)threadIdx.x;
  const int wid  = tid >> 6;
  const int lane = tid & 63;
  const int l15  = lane & 15;
  const int lg   = lane >> 4;

  const int fg = (int)blockIdx.x & (kFG - 1);  // same-f blocks stride 64 apart
  const int rg = (int)blockIdx.x >> 6;
  const int f  = fg * kFPB + wid;          // this wave's feature
  const int r0 = rg * kRPB;

  // ---- w2 fragments: 8 coalesced 16B loads/lane (reused 16 passes) ----
  bf16x8 w2frag[4][2];
  {
    const __bf16* base = w2p + ((size_t)f * 8 * 64 + lane) * 8;
    #pragma unroll
    for (int t = 0; t < 4; ++t)
      #pragma unroll
      for (int ks = 0; ks < 2; ++ks)
        w2frag[t][ks] = *reinterpret_cast<const bf16x8*>(
            base + (size_t)(t * 2 + ks) * 64 * 8);
  }

  // ---- stage x tile (256 rows x 4 feats), transpose into LDS ----
  {
    const int rr = tid;                    // one row per thread
    const f32x4 v = *reinterpret_cast<const f32x4*>(
        x + (size_t)(r0 + rr) * kF + fg * kFPB);
    xs[0][rr] = v[0]; xs[1][rr] = v[1]; xs[2][rr] = v[2]; xs[3][rr] = v[3];
  }

  // ---- per-wave params (tiny, L1/L2-resident) ----
  f32x4 w1v[2][2], b1v[2][2];
  #pragma unroll
  for (int ks = 0; ks < 2; ++ks) {
    const float* pw = w1 + f * kH + ks * 32 + lg * 8;
    const float* pb = b1 + f * kH + ks * 32 + lg * 8;
    w1v[ks][0] = *reinterpret_cast<const f32x4*>(pw);
    w1v[ks][1] = *reinterpret_cast<const f32x4*>(pw + 4);
    b1v[ks][0] = *reinterpret_cast<const f32x4*>(pb);
    b1v[ks][1] = *reinterpret_cast<const f32x4*>(pb + 4);
  }
  f32x4 b2c[4], w3v[4];
  #pragma unroll
  for (int t = 0; t < 4; ++t) {
    b2c[t] = *reinterpret_cast<const f32x4*>(b2 + f * kH + t * 16 + lg * 4);
    w3v[t] = *reinterpret_cast<const f32x4*>(w3 + f * kH + t * 16 + lg * 4);
  }
  const float b3v = b3[f];

  __syncthreads();   // xs ready

  const f32x4 zero4 = {0.f, 0.f, 0.f, 0.f};
  float keep = 0.f;

  #pragma unroll 4
  for (int p = 0; p < kPasses; ++p) {
    const float xv = xs[wid][p * 16 + l15];

    // ---- layer 1: h1 = relu(x*w1 + b1) -> bf16 B-fragments ----
    bf16x8 h1frag[2];
    #pragma unroll
    for (int ks = 0; ks < 2; ++ks) {
      f32x4 a = w1v[ks][0] * xv + b1v[ks][0];
      f32x4 b = w1v[ks][1] * xv + b1v[ks][1];
      a = __builtin_elementwise_max(a, zero4);
      b = __builtin_elementwise_max(b, zero4);
      h1frag[ks] = __builtin_shufflevector(
          __builtin_convertvector(a, bf16x4),
          __builtin_convertvector(b, bf16x4), 0, 1, 2, 3, 4, 5, 6, 7);
    }

    // ---- layer 2 (C init = b2) + layer 3 epilogue ----
    f32x4 p4 = zero4;
    #pragma unroll
    for (int t = 0; t < 4; ++t) {
      f32x4 acc = __builtin_amdgcn_mfma_f32_16x16x32_bf16(
          w2frag[t][0], h1frag[0], b2c[t], 0, 0, 0);
      acc = __builtin_amdgcn_mfma_f32_16x16x32_bf16(
          w2frag[t][1], h1frag[1], acc, 0, 0, 0);
      const f32x4 r = __builtin_elementwise_max(acc, zero4);
      p4 += r * w3v[t];
    }

    float s = (p4[0] + p4[1]) + (p4[2] + p4[3]);
    s += __shfl_xor(s, 16);
    s += __shfl_xor(s, 32);

    keep = (lg == (p & 3)) ? s : keep;
    if ((p & 3) == 3) {
      // rows p-3..p done: lane stores row (quad*64 + lane)
      outb[(p >> 2) * 64 + lane][wid] = keep + b3v;
    }
  }

  __syncthreads();

  // ---- output: one float4 (4 features) per row ----
  {
    const int rr = tid;                    // one row per thread
    const f32x4 v = {outb[rr][0], outb[rr][1], outb[rr][2], outb[rr][3]};
    *reinterpret_cast<f32x4*>(out + (size_t)(r0 + rr) * kF + fg * kFPB) = v;
  }
}

}  // namespace

extern "C" void kernel_launch(void* const* d_in, const int* in_sizes, int n_in,
                              void* d_out, int out_size, void* d_ws, size_t ws_size,
                              hipStream_t stream) {
  const float* x  = (const float*)d_in[0];
  const float* w1 = (const float*)d_in[1];
  const float* b1 = (const float*)d_in[2];
  const float* w2 = (const float*)d_in[3];
  const float* b2 = (const float*)d_in[4];
  const float* w3 = (const float*)d_in[5];
  const float* b3 = (const float*)d_in[6];
  float* out = (float*)d_out;

  __bf16* w2p = (__bf16*)d_ws;            // 256*64*64*2 B = 2 MB

  hipLaunchKernelGGL(pack_w2, dim3(kF / 4), dim3(256), 0, stream, w2, w2p);
  hipLaunchKernelGGL(mlp_pf_v6, dim3(kBlocks), dim3(kThreads), 0, stream,
                     x, w1, b1, w2p, b2, w3, b3, out);
}

// Round 7
// 43.183 us; speedup vs baseline: 9.2825x; 9.2825x over previous
//
#include <hip/hip_runtime.h>
#include <hip/hip_bf16.h>

// MLP_small_per_feature: per-feature MLP 1 -> 64 -> 64 -> 1, F=256, B=8192.
// v7 = v4's proven body (43.4 us) + two occupancy-safe changes:
//  (1) pack_w2 prep kernel -> bf16 fragment-major w2p in d_ws (2 MB, fits
//      every XCD L2). Main-kernel w2 load = 8 coalesced dwordx4 per wave, so
//      wave count no longer multiplies HBM fetch (v5's failure mode).
//  (2) kRPB=128 -> 4096 blocks (16 avail/CU). LDS ~4.6 KB. Residency is now
//      VGPR-capped (64 VGPR -> 8 blocks/CU = 32 waves/CU), not grid-capped.
//  launch_bounds(256,4) EXACTLY as v4: v6 proved (256,8) forces VGPR=32 and
//  spills to scratch (1.3 GB traffic, 400 us). Never again.
//
// MFMA 16x16x32_bf16 layout (verified rounds 1-6, absmax 0.031):
//   A: row m = lane&15, k = (lane>>4)*8 + i
//   B: col n = lane&15, k = (lane>>4)*8 + i
//   C/D: col n = lane&15, row m = (lane>>4)*4 + r

namespace {

constexpr int kF = 256;
constexpr int kH = 64;
constexpr int kB = 8192;

constexpr int kFPB     = 4;               // features per block (one per wave)
constexpr int kRPB     = 128;             // rows per block
constexpr int kThreads = 256;             // 4 waves
constexpr int kFG      = kF / kFPB;       // 64 feature groups
constexpr int kRG      = kB / kRPB;       // 64 row groups
constexpr int kBlocks  = kFG * kRG;       // 4096
constexpr int kPasses  = kRPB / 16;       // 8

using f32x4  = __attribute__((ext_vector_type(4))) float;
using bf16x4 = __attribute__((ext_vector_type(4))) __bf16;
using bf16x8 = __attribute__((ext_vector_type(8))) __bf16;

// ---- prep: pack w2 (fp32 [F][64][64]) -> bf16 fragment-major ----
// w2p elem offset ((f*8 + t*2+ks)*64 + lane)*8; lane l's fragment (t,ks) =
// w2[f][o=t*16+(l&15)][ks*32+(l>>4)*8 .. +8].
__global__ __launch_bounds__(256)
void pack_w2(const float* __restrict__ w2, __bf16* __restrict__ w2p)
{
  const int wid  = (int)threadIdx.x >> 6;
  const int lane = (int)threadIdx.x & 63;
  const int f    = (int)blockIdx.x * 4 + wid;
  const int l15  = lane & 15;
  const int lg   = lane >> 4;

  const float* w2f = w2 + (size_t)f * (kH * kH);
  #pragma unroll
  for (int t = 0; t < 4; ++t) {
    const int o = t * 16 + l15;
    #pragma unroll
    for (int ks = 0; ks < 2; ++ks) {
      const float* p = w2f + o * kH + ks * 32 + lg * 8;
      const f32x4 lo = *reinterpret_cast<const f32x4*>(p);
      const f32x4 hi = *reinterpret_cast<const f32x4*>(p + 4);
      const bf16x8 v = __builtin_shufflevector(
          __builtin_convertvector(lo, bf16x4),
          __builtin_convertvector(hi, bf16x4), 0, 1, 2, 3, 4, 5, 6, 7);
      *reinterpret_cast<bf16x8*>(
          w2p + (((size_t)f * 8 + t * 2 + ks) * 64 + lane) * 8) = v;
    }
  }
}

__global__ __launch_bounds__(kThreads, 4)
void mlp_pf_v7(const float* __restrict__ x,
               const float* __restrict__ w1,
               const float* __restrict__ b1,
               const __bf16* __restrict__ w2p,
               const float* __restrict__ b2,
               const float* __restrict__ w3,
               const float* __restrict__ b3,
               float* __restrict__ out)
{
  __shared__ float xs[kFPB][kRPB];        // 2 KB
  __shared__ float outb[kRPB][kFPB + 1];  // 2.56 KB (pad: conflict-free)

  const int tid  = (int)threadIdx.x;
  const int wid  = tid >> 6;
  const int lane = tid & 63;
  const int l15  = lane & 15;
  const int lg   = lane >> 4;

  const int fg = (int)blockIdx.x & (kFG - 1);  // consecutive blocks: same rows
  const int rg = (int)blockIdx.x >> 6;
  const int f  = fg * kFPB + wid;          // this wave's feature
  const int r0 = rg * kRPB;

  // ---- w2 fragments: 8 coalesced 16B loads/lane (L2-resident w2p) ----
  bf16x8 w2frag[4][2];
  {
    const __bf16* base = w2p + ((size_t)f * 8 * 64 + lane) * 8;
    #pragma unroll
    for (int t = 0; t < 4; ++t)
      #pragma unroll
      for (int ks = 0; ks < 2; ++ks)
        w2frag[t][ks] = *reinterpret_cast<const bf16x8*>(
            base + (size_t)(t * 2 + ks) * 64 * 8);
  }

  // ---- stage x tile (128 rows x 4 feats), transpose into LDS ----
  if (tid < kRPB) {
    const int rr = tid;
    const f32x4 v = *reinterpret_cast<const f32x4*>(
        x + (size_t)(r0 + rr) * kF + fg * kFPB);
    xs[0][rr] = v[0]; xs[1][rr] = v[1]; xs[2][rr] = v[2]; xs[3][rr] = v[3];
  }

  // ---- per-wave params (tiny, L1/L2-resident) ----
  f32x4 w1v[2][2], b1v[2][2];
  #pragma unroll
  for (int ks = 0; ks < 2; ++ks) {
    const float* pw = w1 + f * kH + ks * 32 + lg * 8;
    const float* pb = b1 + f * kH + ks * 32 + lg * 8;
    w1v[ks][0] = *reinterpret_cast<const f32x4*>(pw);
    w1v[ks][1] = *reinterpret_cast<const f32x4*>(pw + 4);
    b1v[ks][0] = *reinterpret_cast<const f32x4*>(pb);
    b1v[ks][1] = *reinterpret_cast<const f32x4*>(pb + 4);
  }
  f32x4 b2c[4], w3v[4];
  #pragma unroll
  for (int t = 0; t < 4; ++t) {
    b2c[t] = *reinterpret_cast<const f32x4*>(b2 + f * kH + t * 16 + lg * 4);
    w3v[t] = *reinterpret_cast<const f32x4*>(w3 + f * kH + t * 16 + lg * 4);
  }
  const float b3v = b3[f];

  __syncthreads();   // xs ready

  const f32x4 zero4 = {0.f, 0.f, 0.f, 0.f};
  float keep = 0.f;

  #pragma unroll 4
  for (int p = 0; p < kPasses; ++p) {
    const float xv = xs[wid][p * 16 + l15];

    // ---- layer 1: h1 = relu(x*w1 + b1) -> bf16 B-fragments ----
    bf16x8 h1frag[2];
    #pragma unroll
    for (int ks = 0; ks < 2; ++ks) {
      f32x4 a = w1v[ks][0] * xv + b1v[ks][0];
      f32x4 b = w1v[ks][1] * xv + b1v[ks][1];
      a = __builtin_elementwise_max(a, zero4);
      b = __builtin_elementwise_max(b, zero4);
      h1frag[ks] = __builtin_shufflevector(
          __builtin_convertvector(a, bf16x4),
          __builtin_convertvector(b, bf16x4), 0, 1, 2, 3, 4, 5, 6, 7);
    }

    // ---- layer 2 (C init = b2) + layer 3 epilogue ----
    f32x4 p4 = zero4;
    #pragma unroll
    for (int t = 0; t < 4; ++t) {
      f32x4 acc = __builtin_amdgcn_mfma_f32_16x16x32_bf16(
          w2frag[t][0], h1frag[0], b2c[t], 0, 0, 0);
      acc = __builtin_amdgcn_mfma_f32_16x16x32_bf16(
          w2frag[t][1], h1frag[1], acc, 0, 0, 0);
      const f32x4 r = __builtin_elementwise_max(acc, zero4);
      p4 += r * w3v[t];
    }

    float s = (p4[0] + p4[1]) + (p4[2] + p4[3]);
    s += __shfl_xor(s, 16);
    s += __shfl_xor(s, 32);

    keep = (lg == (p & 3)) ? s : keep;
    if ((p & 3) == 3) {
      // rows p-3..p done: lane stores row (quad*64 + lane)
      outb[(p >> 2) * 64 + lane][wid] = keep + b3v;
    }
  }

  __syncthreads();

  // ---- output: one float4 (4 features) per row ----
  if (tid < kRPB) {
    const int rr = tid;
    const f32x4 v = {outb[rr][0], outb[rr][1], outb[rr][2], outb[rr][3]};
    *reinterpret_cast<f32x4*>(out + (size_t)(r0 + rr) * kF + fg * kFPB) = v;
  }
}

}  // namespace

extern "C" void kernel_launch(void* const* d_in, const int* in_sizes, int n_in,
                              void* d_out, int out_size, void* d_ws, size_t ws_size,
                              hipStream_t stream) {
  const float* x  = (const float*)d_in[0];
  const float* w1 = (const float*)d_in[1];
  const float* b1 = (const float*)d_in[2];
  const float* w2 = (const float*)d_in[3];
  const float* b2 = (const float*)d_in[4];
  const float* w3 = (const float*)d_in[5];
  const float* b3 = (const float*)d_in[6];
  float* out = (float*)d_out;

  __bf16* w2p = (__bf16*)d_ws;            // 256*64*64*2 B = 2 MB

  hipLaunchKernelGGL(pack_w2, dim3(kF / 4), dim3(256), 0, stream, w2, w2p);
  hipLaunchKernelGGL(mlp_pf_v7, dim3(kBlocks), dim3(kThreads), 0, stream,
                     x, w1, b1, w2p, b2, w3, b3, out);
}